// Round 4
// baseline (9061.684 us; speedup 1.0000x reference)
//
#include <hip/hip_runtime.h>
#include <cstdint>
#include <cstddef>

#define L_SEQ 2048
#define H_DIM 1024
#define NBLK  128     // scan blocks per sequence (8 rows each)
#define SCAN_T 512    // threads per scan block (8 waves, 1 row per wave)

typedef unsigned long long u64;

__device__ __forceinline__ float sigmoid_f(float x) {
  return 1.0f / (1.0f + __expf(-x));
}
__device__ __forceinline__ float tanh_f(float x) {
  return 1.0f - 2.0f / (__expf(2.0f * x) + 1.0f);
}

// ---------------------------------------------------------------------------
// init: pack h0 with tag 0 into parity-buffer 0; sentinel tags into buffer 1
// ---------------------------------------------------------------------------
__global__ void init_kernel(const float* __restrict__ h01, const float* __restrict__ h02,
                            u64* __restrict__ hb1, u64* __restrict__ hb2) {
  const int tid = threadIdx.x;  // 256 threads
  for (int i = tid; i < H_DIM; i += 256) {
    hb1[i] = (u64)__float_as_uint(h01[i]);          // tag 0 | h0 bits
    hb2[i] = (u64)__float_as_uint(h02[i]);
    hb1[H_DIM + i] = 0x7FFFFFFFull << 32;           // sentinel tag (never matches)
    hb2[H_DIM + i] = 0x7FFFFFFFull << 32;
  }
}

// ---------------------------------------------------------------------------
// gx = emb[tok] @ W_ih^T + (b_ih + b_hh)   for both sequences
// fused-gather fp32 GEMM: 128x128 tile, BK=16, 256 threads, 8x8 microtile
// ---------------------------------------------------------------------------
__global__ __launch_bounds__(256) void gemm_gx_kernel(
    const int* __restrict__ s1, const int* __restrict__ s2,
    const float* __restrict__ emb, const float* __restrict__ W_ih,
    const float* __restrict__ b_ih, const float* __restrict__ b_hh,
    float* __restrict__ gx1, float* __restrict__ gx2) {
  const int seq = blockIdx.z;
  const int* __restrict__ tok = seq ? s2 : s1;
  float* __restrict__ gx = seq ? gx2 : gx1;
  const int m0 = blockIdx.y * 128;  // token rows
  const int n0 = blockIdx.x * 128;  // gate rows
  const int tid = threadIdx.x;
  const int ti = tid >> 4;   // 0..15
  const int tj = tid & 15;   // 0..15

  __shared__ float As[16][128];
  __shared__ float Bs[16][128];

  const int lr  = tid >> 1;         // 0..127: tile row this thread loads
  const int lk0 = (tid & 1) * 8;    // k-half
  const int arow = tok[m0 + lr];
  const float* aptr = emb + (size_t)arow * H_DIM + lk0;
  const float* bptr = W_ih + (size_t)(n0 + lr) * H_DIM + lk0;

  float acc[8][8];
#pragma unroll
  for (int i = 0; i < 8; ++i)
#pragma unroll
    for (int jj = 0; jj < 8; ++jj) acc[i][jj] = 0.f;

  for (int k0 = 0; k0 < H_DIM; k0 += 16) {
    const float4 av0 = *(const float4*)(aptr + k0);
    const float4 av1 = *(const float4*)(aptr + k0 + 4);
    const float4 bv0 = *(const float4*)(bptr + k0);
    const float4 bv1 = *(const float4*)(bptr + k0 + 4);
    __syncthreads();  // protect previous iteration's LDS reads
    As[lk0 + 0][lr] = av0.x; As[lk0 + 1][lr] = av0.y;
    As[lk0 + 2][lr] = av0.z; As[lk0 + 3][lr] = av0.w;
    As[lk0 + 4][lr] = av1.x; As[lk0 + 5][lr] = av1.y;
    As[lk0 + 6][lr] = av1.z; As[lk0 + 7][lr] = av1.w;
    Bs[lk0 + 0][lr] = bv0.x; Bs[lk0 + 1][lr] = bv0.y;
    Bs[lk0 + 2][lr] = bv0.z; Bs[lk0 + 3][lr] = bv0.w;
    Bs[lk0 + 4][lr] = bv1.x; Bs[lk0 + 5][lr] = bv1.y;
    Bs[lk0 + 6][lr] = bv1.z; Bs[lk0 + 7][lr] = bv1.w;
    __syncthreads();
#pragma unroll
    for (int k = 0; k < 16; ++k) {
      float a[8], bb[8];
      *(float4*)&a[0]  = *(const float4*)&As[k][ti * 8];
      *(float4*)&a[4]  = *(const float4*)&As[k][ti * 8 + 4];
      *(float4*)&bb[0] = *(const float4*)&Bs[k][tj * 8];
      *(float4*)&bb[4] = *(const float4*)&Bs[k][tj * 8 + 4];
#pragma unroll
      for (int i = 0; i < 8; ++i)
#pragma unroll
        for (int jj = 0; jj < 8; ++jj)
          acc[i][jj] = fmaf(a[i], bb[jj], acc[i][jj]);
    }
  }

  float bias[8];
#pragma unroll
  for (int jj = 0; jj < 8; ++jj) {
    const int n = n0 + tj * 8 + jj;
    bias[jj] = b_ih[n] + b_hh[n];
  }
#pragma unroll
  for (int i = 0; i < 8; ++i) {
    const int m = m0 + ti * 8 + i;
    float* dst = gx + (size_t)m * (4 * H_DIM) + n0 + tj * 8;
    float4 o0 = make_float4(acc[i][0] + bias[0], acc[i][1] + bias[1],
                            acc[i][2] + bias[2], acc[i][3] + bias[3]);
    float4 o1 = make_float4(acc[i][4] + bias[4], acc[i][5] + bias[5],
                            acc[i][6] + bias[6], acc[i][7] + bias[7]);
    *(float4*)dst = o0;
    *(float4*)(dst + 4) = o1;
  }
}

// ---------------------------------------------------------------------------
// persistent LSTM scan, tag-embedded h protocol, wave-per-row decomposition.
// 128 blocks/sequence; block b owns rows [b*8, b*8+8). Wave g owns row
// j=b*8+g; lane u owns k-slice [u*16,u*16+16) for all 4 gates -> 64 weight
// floats/thread. ALL weight accesses use literal indices (macro-expanded) so
// SROA promotes the array to SSA registers (dynamic indices -> scratch,
// which was rounds 1-3's hidden cost: VGPR_Count 56-84, scratch re-read
// every step). __launch_bounds__(512,2) -> 256-VGPR budget, no spill.
// Per step: lane0 rotate-prefetches gx[t+1]; all threads poll their 2
// h-words (tag embedded in the same 64b atom, s_sleep backoff to cut LLC
// poll bandwidth); unpack into LDS parity buffer (ONE barrier/step);
// 64 literal-index FMAs; 64-lane butterfly; lane 0 gates + publish.
// ---------------------------------------------------------------------------
__global__ __launch_bounds__(SCAN_T, 2) void lstm_scan_kernel(
    const float* __restrict__ W_hh,
    const float* __restrict__ gx1, const float* __restrict__ gx2,
    const float* __restrict__ c01, const float* __restrict__ c02,
    u64* __restrict__ hb1, u64* __restrict__ hb2) {
  const int blk = blockIdx.x;
  const int seq = (blk >= NBLK) ? 1 : 0;
  const int b = blk - seq * NBLK;
  const float* __restrict__ gx = seq ? gx2 : gx1;
  u64* hb = seq ? hb2 : hb1;
  const float* c0 = seq ? c02 : c01;

  const int tid = threadIdx.x;
  const int g = tid >> 6;       // 0..7  : wave = row
  const int u = tid & 63;       // 0..63 : k-slice of 16
  const int j = b * 8 + g;      // owned output row

  // weight slice pointers, one per gate (literal gate index)
  const float* wp0 = W_hh + (((size_t)(0 * H_DIM + j)) << 10) + (u << 4);
  const float* wp1 = W_hh + (((size_t)(1 * H_DIM + j)) << 10) + (u << 4);
  const float* wp2 = W_hh + (((size_t)(2 * H_DIM + j)) << 10) + (u << 4);
  const float* wp3 = W_hh + (((size_t)(3 * H_DIM + j)) << 10) + (u << 4);

  float w[4][16];
#define LDW(q, i) do { const float4 v = *(const float4*)(wp##q + (i) * 4); \
    w[q][(i)*4+0] = v.x; w[q][(i)*4+1] = v.y;                              \
    w[q][(i)*4+2] = v.z; w[q][(i)*4+3] = v.w; } while (0)
  LDW(0,0); LDW(0,1); LDW(0,2); LDW(0,3);
  LDW(1,0); LDW(1,1); LDW(1,2); LDW(1,3);
  LDW(2,0); LDW(2,1); LDW(2,2); LDW(2,3);
  LDW(3,0); LDW(3,1); LDW(3,2); LDW(3,3);
#undef LDW
#define PIN16(q) asm volatile("" \
    : "+v"(w[q][0]),  "+v"(w[q][1]),  "+v"(w[q][2]),  "+v"(w[q][3]),   \
      "+v"(w[q][4]),  "+v"(w[q][5]),  "+v"(w[q][6]),  "+v"(w[q][7]),   \
      "+v"(w[q][8]),  "+v"(w[q][9]),  "+v"(w[q][10]), "+v"(w[q][11]),  \
      "+v"(w[q][12]), "+v"(w[q][13]), "+v"(w[q][14]), "+v"(w[q][15]))
  PIN16(0); PIN16(1); PIN16(2); PIN16(3);
#undef PIN16

  float c = (u == 0) ? c0[j] : 0.0f;

  __shared__ float sh[2][32 * 34];  // parity dbuf; stride 34: 8B-aligned, <=2-way

  const int i0 = tid * 2;           // this thread's 2 h-word slots
  const int stg = (i0 >> 5) * 34 + (i0 & 31);          // staging offset (floats)
  const int rdo = (u >> 1) * 34 + (u & 1) * 16;        // read offset (floats)

  // gx prefetch: current-step values in gxc*, next-step issued each iter
  float gxc0 = 0.f, gxc1 = 0.f, gxc2 = 0.f, gxc3 = 0.f;
  if (u == 0) {
    const float* gp = gx + j;
    gxc0 = gp[0];
    gxc1 = gp[H_DIM];
    gxc2 = gp[2 * H_DIM];
    gxc3 = gp[3 * H_DIM];
  }

  for (int t = 0; t < L_SEQ; ++t) {
    // issue next step's gx loads (hidden under this step's poll + compute)
    float gxn0 = 0.f, gxn1 = 0.f, gxn2 = 0.f, gxn3 = 0.f;
    if (u == 0) {
      const int tp = (t + 1 < L_SEQ) ? t + 1 : t;
      const float* gp = gx + (size_t)tp * (4 * H_DIM) + j;
      gxn0 = gp[0];
      gxn1 = gp[H_DIM];
      gxn2 = gp[2 * H_DIM];
      gxn3 = gp[3 * H_DIM];
    }
    // poll both h-words; tag embedded in same atom; sleep-backoff on miss
    const u64* src = hb + ((t & 1) << 10) + i0;
    const unsigned tg = (unsigned)t;
    u64 w0, w1;
    for (;;) {
      w0 = __hip_atomic_load(src,     __ATOMIC_RELAXED, __HIP_MEMORY_SCOPE_AGENT);
      w1 = __hip_atomic_load(src + 1, __ATOMIC_RELAXED, __HIP_MEMORY_SCOPE_AGENT);
      if (((unsigned)(w0 >> 32) == tg) & ((unsigned)(w1 >> 32) == tg)) break;
      __builtin_amdgcn_s_sleep(1);
    }
    float* sb = &sh[t & 1][0];
    float2 hv2 = make_float2(__uint_as_float((unsigned)w0),
                             __uint_as_float((unsigned)w1));
    *(float2*)(sb + stg) = hv2;
    __syncthreads();  // the only barrier per step (parity dbuf covers WAR)
    // partial dot products for all 4 gates, literal indices throughout
    const float* hs = sb + rdo;
    float a0 = 0.f, a1 = 0.f, a2 = 0.f, a3 = 0.f;
#define FMA_STEP(kk) do { const float hv = hs[kk]; \
    a0 = fmaf(w[0][kk], hv, a0); a1 = fmaf(w[1][kk], hv, a1); \
    a2 = fmaf(w[2][kk], hv, a2); a3 = fmaf(w[3][kk], hv, a3); } while (0)
    FMA_STEP(0);  FMA_STEP(1);  FMA_STEP(2);  FMA_STEP(3);
    FMA_STEP(4);  FMA_STEP(5);  FMA_STEP(6);  FMA_STEP(7);
    FMA_STEP(8);  FMA_STEP(9);  FMA_STEP(10); FMA_STEP(11);
    FMA_STEP(12); FMA_STEP(13); FMA_STEP(14); FMA_STEP(15);
#undef FMA_STEP
    // 64-lane butterfly reduce
#pragma unroll
    for (int offx = 32; offx >= 1; offx >>= 1) {
      a0 += __shfl_xor(a0, offx);
      a1 += __shfl_xor(a1, offx);
      a2 += __shfl_xor(a2, offx);
      a3 += __shfl_xor(a3, offx);
    }
    if (u == 0) {
      const float gi = a0 + gxc0;
      const float gf = a1 + gxc1;
      const float gg = a2 + gxc2;
      const float go = a3 + gxc3;
      c = sigmoid_f(gf) * c + sigmoid_f(gi) * tanh_f(gg);
      const float hn = sigmoid_f(go) * tanh_f(c);
      const u64 pk = ((u64)(unsigned)(t + 1) << 32) | (u64)__float_as_uint(hn);
      __hip_atomic_store(hb + (((t + 1) & 1) << 10) + j, pk,
                         __ATOMIC_RELAXED, __HIP_MEMORY_SCOPE_AGENT);
    }
    gxc0 = gxn0; gxc1 = gxn1; gxc2 = gxn2; gxc3 = gxn3;
  }
}

// ---------------------------------------------------------------------------
// head: feat = [v1, v2, |v1-v2|, v1*v2]; out = fc2_w @ (fc1_w@feat + fc1_b) + fc2_b
// reads the packed final-h buffers (parity 0 holds tag-2048 values)
// ---------------------------------------------------------------------------
__global__ __launch_bounds__(512) void head_kernel(
    const u64* __restrict__ h1p, const u64* __restrict__ h2p,
    const float* __restrict__ fc1_w, const float* __restrict__ fc1_b,
    const float* __restrict__ fc2_w, const float* __restrict__ fc2_b,
    float* __restrict__ out) {
  __shared__ float feat[4 * H_DIM];
  __shared__ float yv[512];
  const int tid = threadIdx.x;
  for (int i = tid; i < H_DIM; i += 512) {
    const float a = __uint_as_float((unsigned)h1p[i]);
    const float bsv = __uint_as_float((unsigned)h2p[i]);
    feat[i] = a;
    feat[H_DIM + i] = bsv;
    feat[2 * H_DIM + i] = fabsf(a - bsv);
    feat[3 * H_DIM + i] = a * bsv;
  }
  __syncthreads();
  float s = fc1_b[tid];
  const float4* wr = (const float4*)(fc1_w + (size_t)tid * (4 * H_DIM));
#pragma unroll 4
  for (int k4 = 0; k4 < H_DIM; ++k4) {
    const float4 wv = wr[k4];
    const float4 fv = *(const float4*)&feat[k4 * 4];
    s = fmaf(wv.x, fv.x, s);
    s = fmaf(wv.y, fv.y, s);
    s = fmaf(wv.z, fv.z, s);
    s = fmaf(wv.w, fv.w, s);
  }
  yv[tid] = s;
  __syncthreads();
  if (tid < 64) {
    float s0 = 0.f, s1 = 0.f;
    for (int i = tid; i < 512; i += 64) {
      s0 = fmaf(fc2_w[i], yv[i], s0);
      s1 = fmaf(fc2_w[512 + i], yv[i], s1);
    }
#pragma unroll
    for (int off = 32; off >= 1; off >>= 1) {
      s0 += __shfl_down(s0, off);
      s1 += __shfl_down(s1, off);
    }
    if (tid == 0) {
      out[0] = s0 + fc2_b[0];
      out[1] = s1 + fc2_b[1];
    }
  }
}

// ---------------------------------------------------------------------------
extern "C" void kernel_launch(void* const* d_in, const int* in_sizes, int n_in,
                              void* d_out, int out_size, void* d_ws, size_t ws_size,
                              hipStream_t stream) {
  const int*   s1    = (const int*)  d_in[0];
  const int*   s2    = (const int*)  d_in[1];
  const float* emb   = (const float*)d_in[2];
  const float* W_ih  = (const float*)d_in[3];
  const float* W_hh  = (const float*)d_in[4];
  const float* b_ih  = (const float*)d_in[5];
  const float* b_hh  = (const float*)d_in[6];
  const float* h01   = (const float*)d_in[7];
  const float* c01   = (const float*)d_in[8];
  const float* h02   = (const float*)d_in[9];
  const float* c02   = (const float*)d_in[10];
  const float* fc1_w = (const float*)d_in[11];
  const float* fc1_b = (const float*)d_in[12];
  const float* fc2_w = (const float*)d_in[13];
  const float* fc2_b = (const float*)d_in[14];
  float* out = (float*)d_out;

  // workspace layout
  const size_t GX = (size_t)L_SEQ * 4 * H_DIM;  // 8M floats per sequence
  float* ws = (float*)d_ws;
  float* gx1 = ws;
  float* gx2 = ws + GX;
  u64* hb1 = (u64*)(ws + 2 * GX);      // [2][1024] packed (tag|h) double buffer
  u64* hb2 = hb1 + 2 * H_DIM;

  init_kernel<<<1, 256, 0, stream>>>(h01, h02, hb1, hb2);

  gemm_gx_kernel<<<dim3(32, 16, 2), 256, 0, stream>>>(
      s1, s2, emb, W_ih, b_ih, b_hh, gx1, gx2);

  void* args[] = { (void*)&W_hh, (void*)&gx1, (void*)&gx2, (void*)&c01,
                   (void*)&c02, (void*)&hb1, (void*)&hb2 };
  hipLaunchCooperativeKernel(reinterpret_cast<void*>(lstm_scan_kernel),
                             dim3(2 * NBLK), dim3(SCAN_T), args, 0, stream);

  head_kernel<<<1, 512, 0, stream>>>(hb1, hb2, fc1_w, fc1_b, fc2_w, fc2_b, out);
}

// Round 5
// 8314.433 us; speedup vs baseline: 1.0899x; 1.0899x over previous
//
#include <hip/hip_runtime.h>
#include <cstdint>
#include <cstddef>

#define L_SEQ 2048
#define H_DIM 1024
#define NBLK  64      // scan blocks per sequence (16 rows each)
#define SCAN_T 1024   // threads per scan block (16 waves, 1 row per wave)

typedef unsigned long long u64;

__device__ __forceinline__ float sigmoid_f(float x) {
  return 1.0f / (1.0f + __expf(-x));
}
__device__ __forceinline__ float tanh_f(float x) {
  return 1.0f - 2.0f / (__expf(2.0f * x) + 1.0f);
}

// ---------------------------------------------------------------------------
// init: pack h0 with tag 0 into parity-buffer 0; sentinel tags into buffer 1
// ---------------------------------------------------------------------------
__global__ void init_kernel(const float* __restrict__ h01, const float* __restrict__ h02,
                            u64* __restrict__ hb1, u64* __restrict__ hb2) {
  const int tid = threadIdx.x;  // 256 threads
  for (int i = tid; i < H_DIM; i += 256) {
    hb1[i] = (u64)__float_as_uint(h01[i]);          // tag 0 | h0 bits
    hb2[i] = (u64)__float_as_uint(h02[i]);
    hb1[H_DIM + i] = 0x7FFFFFFFull << 32;           // sentinel tag (never matches)
    hb2[H_DIM + i] = 0x7FFFFFFFull << 32;
  }
}

// ---------------------------------------------------------------------------
// gx = emb[tok] @ W_ih^T + (b_ih + b_hh)   for both sequences
// fused-gather fp32 GEMM: 128x128 tile, BK=16, 256 threads, 8x8 microtile
// ---------------------------------------------------------------------------
__global__ __launch_bounds__(256) void gemm_gx_kernel(
    const int* __restrict__ s1, const int* __restrict__ s2,
    const float* __restrict__ emb, const float* __restrict__ W_ih,
    const float* __restrict__ b_ih, const float* __restrict__ b_hh,
    float* __restrict__ gx1, float* __restrict__ gx2) {
  const int seq = blockIdx.z;
  const int* __restrict__ tok = seq ? s2 : s1;
  float* __restrict__ gx = seq ? gx2 : gx1;
  const int m0 = blockIdx.y * 128;  // token rows
  const int n0 = blockIdx.x * 128;  // gate rows
  const int tid = threadIdx.x;
  const int ti = tid >> 4;   // 0..15
  const int tj = tid & 15;   // 0..15

  __shared__ float As[16][128];
  __shared__ float Bs[16][128];

  const int lr  = tid >> 1;         // 0..127: tile row this thread loads
  const int lk0 = (tid & 1) * 8;    // k-half
  const int arow = tok[m0 + lr];
  const float* aptr = emb + (size_t)arow * H_DIM + lk0;
  const float* bptr = W_ih + (size_t)(n0 + lr) * H_DIM + lk0;

  float acc[8][8];
#pragma unroll
  for (int i = 0; i < 8; ++i)
#pragma unroll
    for (int jj = 0; jj < 8; ++jj) acc[i][jj] = 0.f;

  for (int k0 = 0; k0 < H_DIM; k0 += 16) {
    const float4 av0 = *(const float4*)(aptr + k0);
    const float4 av1 = *(const float4*)(aptr + k0 + 4);
    const float4 bv0 = *(const float4*)(bptr + k0);
    const float4 bv1 = *(const float4*)(bptr + k0 + 4);
    __syncthreads();  // protect previous iteration's LDS reads
    As[lk0 + 0][lr] = av0.x; As[lk0 + 1][lr] = av0.y;
    As[lk0 + 2][lr] = av0.z; As[lk0 + 3][lr] = av0.w;
    As[lk0 + 4][lr] = av1.x; As[lk0 + 5][lr] = av1.y;
    As[lk0 + 6][lr] = av1.z; As[lk0 + 7][lr] = av1.w;
    Bs[lk0 + 0][lr] = bv0.x; Bs[lk0 + 1][lr] = bv0.y;
    Bs[lk0 + 2][lr] = bv0.z; Bs[lk0 + 3][lr] = bv0.w;
    Bs[lk0 + 4][lr] = bv1.x; Bs[lk0 + 5][lr] = bv1.y;
    Bs[lk0 + 6][lr] = bv1.z; Bs[lk0 + 7][lr] = bv1.w;
    __syncthreads();
#pragma unroll
    for (int k = 0; k < 16; ++k) {
      float a[8], bb[8];
      *(float4*)&a[0]  = *(const float4*)&As[k][ti * 8];
      *(float4*)&a[4]  = *(const float4*)&As[k][ti * 8 + 4];
      *(float4*)&bb[0] = *(const float4*)&Bs[k][tj * 8];
      *(float4*)&bb[4] = *(const float4*)&Bs[k][tj * 8 + 4];
#pragma unroll
      for (int i = 0; i < 8; ++i)
#pragma unroll
        for (int jj = 0; jj < 8; ++jj)
          acc[i][jj] = fmaf(a[i], bb[jj], acc[i][jj]);
    }
  }

  float bias[8];
#pragma unroll
  for (int jj = 0; jj < 8; ++jj) {
    const int n = n0 + tj * 8 + jj;
    bias[jj] = b_ih[n] + b_hh[n];
  }
#pragma unroll
  for (int i = 0; i < 8; ++i) {
    const int m = m0 + ti * 8 + i;
    float* dst = gx + (size_t)m * (4 * H_DIM) + n0 + tj * 8;
    float4 o0 = make_float4(acc[i][0] + bias[0], acc[i][1] + bias[1],
                            acc[i][2] + bias[2], acc[i][3] + bias[3]);
    float4 o1 = make_float4(acc[i][4] + bias[4], acc[i][5] + bias[5],
                            acc[i][6] + bias[6], acc[i][7] + bias[7]);
    *(float4*)dst = o0;
    *(float4*)(dst + 4) = o1;
  }
}

// ---------------------------------------------------------------------------
// persistent LSTM scan, tag-embedded h protocol, wave-per-row, 1024 threads.
// 64 blocks/sequence (128 total -> same contention point as the best round).
// Block b owns rows [b*16, b*16+16); wave g owns row j=b*16+g; lane u owns
// k-slice [u*16,u*16+16) for all 4 gates -> 64 weight floats/thread,
// literal-index loads only (SROA-promotable), no asm pin.
// __launch_bounds__(1024,4) caps regs at 128: 64 weights + ~40 work fits.
// Per step: lane0 rotate-prefetches gx[t+1]; each of the 1024 threads polls
// exactly ONE h-word (tag embedded in the same 64b atom, pure spin);
// stages 1 float into LDS parity buffer (stride 36: 16B-aligned reads);
// ONE barrier; 64 literal-index FMAs; 6-level 64-lane butterfly; lane 0
// does gate math and publishes (tag t+1 | h) as one 64b atom.
// ---------------------------------------------------------------------------
__global__ __launch_bounds__(SCAN_T, 4) void lstm_scan_kernel(
    const float* __restrict__ W_hh,
    const float* __restrict__ gx1, const float* __restrict__ gx2,
    const float* __restrict__ c01, const float* __restrict__ c02,
    u64* __restrict__ hb1, u64* __restrict__ hb2) {
  const int blk = blockIdx.x;
  const int seq = (blk >= NBLK) ? 1 : 0;
  const int b = blk - seq * NBLK;
  const float* __restrict__ gx = seq ? gx2 : gx1;
  u64* hb = seq ? hb2 : hb1;
  const float* c0 = seq ? c02 : c01;

  const int tid = threadIdx.x;
  const int g = tid >> 6;       // 0..15 : wave = row
  const int u = tid & 63;       // 0..63 : k-slice of 16
  const int j = b * 16 + g;     // owned output row

  // weight slice pointers, one per gate (literal gate index)
  const float* wp0 = W_hh + (((size_t)(0 * H_DIM + j)) << 10) + (u << 4);
  const float* wp1 = W_hh + (((size_t)(1 * H_DIM + j)) << 10) + (u << 4);
  const float* wp2 = W_hh + (((size_t)(2 * H_DIM + j)) << 10) + (u << 4);
  const float* wp3 = W_hh + (((size_t)(3 * H_DIM + j)) << 10) + (u << 4);

  float w[4][16];
#define LDW(q, i) do { const float4 v = *(const float4*)(wp##q + (i) * 4); \
    w[q][(i)*4+0] = v.x; w[q][(i)*4+1] = v.y;                              \
    w[q][(i)*4+2] = v.z; w[q][(i)*4+3] = v.w; } while (0)
  LDW(0,0); LDW(0,1); LDW(0,2); LDW(0,3);
  LDW(1,0); LDW(1,1); LDW(1,2); LDW(1,3);
  LDW(2,0); LDW(2,1); LDW(2,2); LDW(2,3);
  LDW(3,0); LDW(3,1); LDW(3,2); LDW(3,3);
#undef LDW

  float c = (u == 0) ? c0[j] : 0.0f;

  // parity double buffer; stride 36 floats: 16B-aligned 16-wide slices,
  // writer 1 float/thread conflict-free, reader <=4-way (off critical path)
  __shared__ float sh[2][32 * 36];

  const int stg = ((tid >> 5) * 36) + (tid & 31);       // staging offset
  const int rdo = ((u >> 1) * 36) + (u & 1) * 16;       // read offset

  // gx prefetch: current-step values in gxc*, next-step issued each iter
  float gxc0 = 0.f, gxc1 = 0.f, gxc2 = 0.f, gxc3 = 0.f;
  if (u == 0) {
    const float* gp = gx + j;
    gxc0 = gp[0];
    gxc1 = gp[H_DIM];
    gxc2 = gp[2 * H_DIM];
    gxc3 = gp[3 * H_DIM];
  }

  for (int t = 0; t < L_SEQ; ++t) {
    // issue next step's gx loads (hidden under this step's poll + compute)
    float gxn0 = 0.f, gxn1 = 0.f, gxn2 = 0.f, gxn3 = 0.f;
    if (u == 0) {
      const int tp = (t + 1 < L_SEQ) ? t + 1 : t;
      const float* gp = gx + (size_t)tp * (4 * H_DIM) + j;
      gxn0 = gp[0];
      gxn1 = gp[H_DIM];
      gxn2 = gp[2 * H_DIM];
      gxn3 = gp[3 * H_DIM];
    }
    // poll this thread's single h-word (tag embedded in the same atom)
    const u64* src = hb + ((t & 1) << 10) + tid;
    const unsigned tg = (unsigned)t;
    u64 w0;
    do {
      w0 = __hip_atomic_load(src, __ATOMIC_RELAXED, __HIP_MEMORY_SCOPE_AGENT);
    } while ((unsigned)(w0 >> 32) != tg);
    float* sb = &sh[t & 1][0];
    sb[stg] = __uint_as_float((unsigned)w0);
    __syncthreads();  // the only barrier per step (parity dbuf covers WAR)
    // partial dot products for all 4 gates, literal indices throughout
    const float* hs = sb + rdo;
    float a0 = 0.f, a1 = 0.f, a2 = 0.f, a3 = 0.f;
#define FMA_STEP(kk) do { const float hv = hs[kk]; \
    a0 = fmaf(w[0][kk], hv, a0); a1 = fmaf(w[1][kk], hv, a1); \
    a2 = fmaf(w[2][kk], hv, a2); a3 = fmaf(w[3][kk], hv, a3); } while (0)
    FMA_STEP(0);  FMA_STEP(1);  FMA_STEP(2);  FMA_STEP(3);
    FMA_STEP(4);  FMA_STEP(5);  FMA_STEP(6);  FMA_STEP(7);
    FMA_STEP(8);  FMA_STEP(9);  FMA_STEP(10); FMA_STEP(11);
    FMA_STEP(12); FMA_STEP(13); FMA_STEP(14); FMA_STEP(15);
#undef FMA_STEP
    // 64-lane butterfly reduce
#pragma unroll
    for (int offx = 32; offx >= 1; offx >>= 1) {
      a0 += __shfl_xor(a0, offx);
      a1 += __shfl_xor(a1, offx);
      a2 += __shfl_xor(a2, offx);
      a3 += __shfl_xor(a3, offx);
    }
    if (u == 0) {
      const float gi = a0 + gxc0;
      const float gf = a1 + gxc1;
      const float gg = a2 + gxc2;
      const float go = a3 + gxc3;
      c = sigmoid_f(gf) * c + sigmoid_f(gi) * tanh_f(gg);
      const float hn = sigmoid_f(go) * tanh_f(c);
      const u64 pk = ((u64)(unsigned)(t + 1) << 32) | (u64)__float_as_uint(hn);
      __hip_atomic_store(hb + (((t + 1) & 1) << 10) + j, pk,
                         __ATOMIC_RELAXED, __HIP_MEMORY_SCOPE_AGENT);
    }
    gxc0 = gxn0; gxc1 = gxn1; gxc2 = gxn2; gxc3 = gxn3;
  }
}

// ---------------------------------------------------------------------------
// head: feat = [v1, v2, |v1-v2|, v1*v2]; out = fc2_w @ (fc1_w@feat + fc1_b) + fc2_b
// reads the packed final-h buffers (parity 0 holds tag-2048 values)
// ---------------------------------------------------------------------------
__global__ __launch_bounds__(512) void head_kernel(
    const u64* __restrict__ h1p, const u64* __restrict__ h2p,
    const float* __restrict__ fc1_w, const float* __restrict__ fc1_b,
    const float* __restrict__ fc2_w, const float* __restrict__ fc2_b,
    float* __restrict__ out) {
  __shared__ float feat[4 * H_DIM];
  __shared__ float yv[512];
  const int tid = threadIdx.x;
  for (int i = tid; i < H_DIM; i += 512) {
    const float a = __uint_as_float((unsigned)h1p[i]);
    const float bsv = __uint_as_float((unsigned)h2p[i]);
    feat[i] = a;
    feat[H_DIM + i] = bsv;
    feat[2 * H_DIM + i] = fabsf(a - bsv);
    feat[3 * H_DIM + i] = a * bsv;
  }
  __syncthreads();
  float s = fc1_b[tid];
  const float4* wr = (const float4*)(fc1_w + (size_t)tid * (4 * H_DIM));
#pragma unroll 4
  for (int k4 = 0; k4 < H_DIM; ++k4) {
    const float4 wv = wr[k4];
    const float4 fv = *(const float4*)&feat[k4 * 4];
    s = fmaf(wv.x, fv.x, s);
    s = fmaf(wv.y, fv.y, s);
    s = fmaf(wv.z, fv.z, s);
    s = fmaf(wv.w, fv.w, s);
  }
  yv[tid] = s;
  __syncthreads();
  if (tid < 64) {
    float s0 = 0.f, s1 = 0.f;
    for (int i = tid; i < 512; i += 64) {
      s0 = fmaf(fc2_w[i], yv[i], s0);
      s1 = fmaf(fc2_w[512 + i], yv[i], s1);
    }
#pragma unroll
    for (int off = 32; off >= 1; off >>= 1) {
      s0 += __shfl_down(s0, off);
      s1 += __shfl_down(s1, off);
    }
    if (tid == 0) {
      out[0] = s0 + fc2_b[0];
      out[1] = s1 + fc2_b[1];
    }
  }
}

// ---------------------------------------------------------------------------
extern "C" void kernel_launch(void* const* d_in, const int* in_sizes, int n_in,
                              void* d_out, int out_size, void* d_ws, size_t ws_size,
                              hipStream_t stream) {
  const int*   s1    = (const int*)  d_in[0];
  const int*   s2    = (const int*)  d_in[1];
  const float* emb   = (const float*)d_in[2];
  const float* W_ih  = (const float*)d_in[3];
  const float* W_hh  = (const float*)d_in[4];
  const float* b_ih  = (const float*)d_in[5];
  const float* b_hh  = (const float*)d_in[6];
  const float* h01   = (const float*)d_in[7];
  const float* c01   = (const float*)d_in[8];
  const float* h02   = (const float*)d_in[9];
  const float* c02   = (const float*)d_in[10];
  const float* fc1_w = (const float*)d_in[11];
  const float* fc1_b = (const float*)d_in[12];
  const float* fc2_w = (const float*)d_in[13];
  const float* fc2_b = (const float*)d_in[14];
  float* out = (float*)d_out;

  // workspace layout
  const size_t GX = (size_t)L_SEQ * 4 * H_DIM;  // 8M floats per sequence
  float* ws = (float*)d_ws;
  float* gx1 = ws;
  float* gx2 = ws + GX;
  u64* hb1 = (u64*)(ws + 2 * GX);      // [2][1024] packed (tag|h) double buffer
  u64* hb2 = hb1 + 2 * H_DIM;

  init_kernel<<<1, 256, 0, stream>>>(h01, h02, hb1, hb2);

  gemm_gx_kernel<<<dim3(32, 16, 2), 256, 0, stream>>>(
      s1, s2, emb, W_ih, b_ih, b_hh, gx1, gx2);

  void* args[] = { (void*)&W_hh, (void*)&gx1, (void*)&gx2, (void*)&c01,
                   (void*)&c02, (void*)&hb1, (void*)&hb2 };
  hipLaunchCooperativeKernel(reinterpret_cast<void*>(lstm_scan_kernel),
                             dim3(2 * NBLK), dim3(SCAN_T), args, 0, stream);

  head_kernel<<<1, 512, 0, stream>>>(hb1, hb2, fc1_w, fc1_b, fc2_w, fc2_b, out);
}

// Round 6
// 6930.333 us; speedup vs baseline: 1.3075x; 1.1997x over previous
//
#include <hip/hip_runtime.h>
#include <cstdint>
#include <cstddef>

#define L_SEQ 2048
#define H_DIM 1024
#define NBLK  64      // scan blocks per sequence (16 rows each)
#define SCAN_T 512    // threads per scan block

typedef unsigned long long u64;
typedef __attribute__((ext_vector_type(4))) float f32x4;

__device__ __forceinline__ float sigmoid_f(float x) {
  return 1.0f / (1.0f + __expf(-x));
}
__device__ __forceinline__ float tanh_f(float x) {
  return 1.0f - 2.0f / (__expf(2.0f * x) + 1.0f);
}

// ---------------------------------------------------------------------------
// init: pack h0 with tag 0 into parity-buffer 0; sentinel tags into buffer 1
// ---------------------------------------------------------------------------
__global__ void init_kernel(const float* __restrict__ h01, const float* __restrict__ h02,
                            u64* __restrict__ hb1, u64* __restrict__ hb2) {
  const int tid = threadIdx.x;  // 256 threads
  for (int i = tid; i < H_DIM; i += 256) {
    hb1[i] = (u64)__float_as_uint(h01[i]);          // tag 0 | h0 bits
    hb2[i] = (u64)__float_as_uint(h02[i]);
    hb1[H_DIM + i] = 0x7FFFFFFFull << 32;           // sentinel tag (never matches)
    hb2[H_DIM + i] = 0x7FFFFFFFull << 32;
  }
}

// ---------------------------------------------------------------------------
// gx = emb[tok] @ W_ih^T + (b_ih + b_hh)   for both sequences
// fused-gather fp32 GEMM: 128x128 tile, BK=16, 256 threads, 8x8 microtile
// ---------------------------------------------------------------------------
__global__ __launch_bounds__(256) void gemm_gx_kernel(
    const int* __restrict__ s1, const int* __restrict__ s2,
    const float* __restrict__ emb, const float* __restrict__ W_ih,
    const float* __restrict__ b_ih, const float* __restrict__ b_hh,
    float* __restrict__ gx1, float* __restrict__ gx2) {
  const int seq = blockIdx.z;
  const int* __restrict__ tok = seq ? s2 : s1;
  float* __restrict__ gx = seq ? gx2 : gx1;
  const int m0 = blockIdx.y * 128;  // token rows
  const int n0 = blockIdx.x * 128;  // gate rows
  const int tid = threadIdx.x;
  const int ti = tid >> 4;   // 0..15
  const int tj = tid & 15;   // 0..15

  __shared__ float As[16][128];
  __shared__ float Bs[16][128];

  const int lr  = tid >> 1;         // 0..127: tile row this thread loads
  const int lk0 = (tid & 1) * 8;    // k-half
  const int arow = tok[m0 + lr];
  const float* aptr = emb + (size_t)arow * H_DIM + lk0;
  const float* bptr = W_ih + (size_t)(n0 + lr) * H_DIM + lk0;

  float acc[8][8];
#pragma unroll
  for (int i = 0; i < 8; ++i)
#pragma unroll
    for (int jj = 0; jj < 8; ++jj) acc[i][jj] = 0.f;

  for (int k0 = 0; k0 < H_DIM; k0 += 16) {
    const float4 av0 = *(const float4*)(aptr + k0);
    const float4 av1 = *(const float4*)(aptr + k0 + 4);
    const float4 bv0 = *(const float4*)(bptr + k0);
    const float4 bv1 = *(const float4*)(bptr + k0 + 4);
    __syncthreads();  // protect previous iteration's LDS reads
    As[lk0 + 0][lr] = av0.x; As[lk0 + 1][lr] = av0.y;
    As[lk0 + 2][lr] = av0.z; As[lk0 + 3][lr] = av0.w;
    As[lk0 + 4][lr] = av1.x; As[lk0 + 5][lr] = av1.y;
    As[lk0 + 6][lr] = av1.z; As[lk0 + 7][lr] = av1.w;
    Bs[lk0 + 0][lr] = bv0.x; Bs[lk0 + 1][lr] = bv0.y;
    Bs[lk0 + 2][lr] = bv0.z; Bs[lk0 + 3][lr] = bv0.w;
    Bs[lk0 + 4][lr] = bv1.x; Bs[lk0 + 5][lr] = bv1.y;
    Bs[lk0 + 6][lr] = bv1.z; Bs[lk0 + 7][lr] = bv1.w;
    __syncthreads();
#pragma unroll
    for (int k = 0; k < 16; ++k) {
      float a[8], bb[8];
      *(float4*)&a[0]  = *(const float4*)&As[k][ti * 8];
      *(float4*)&a[4]  = *(const float4*)&As[k][ti * 8 + 4];
      *(float4*)&bb[0] = *(const float4*)&Bs[k][tj * 8];
      *(float4*)&bb[4] = *(const float4*)&Bs[k][tj * 8 + 4];
#pragma unroll
      for (int i = 0; i < 8; ++i)
#pragma unroll
        for (int jj = 0; jj < 8; ++jj)
          acc[i][jj] = fmaf(a[i], bb[jj], acc[i][jj]);
    }
  }

  float bias[8];
#pragma unroll
  for (int jj = 0; jj < 8; ++jj) {
    const int n = n0 + tj * 8 + jj;
    bias[jj] = b_ih[n] + b_hh[n];
  }
#pragma unroll
  for (int i = 0; i < 8; ++i) {
    const int m = m0 + ti * 8 + i;
    float* dst = gx + (size_t)m * (4 * H_DIM) + n0 + tj * 8;
    float4 o0 = make_float4(acc[i][0] + bias[0], acc[i][1] + bias[1],
                            acc[i][2] + bias[2], acc[i][3] + bias[3]);
    float4 o1 = make_float4(acc[i][4] + bias[4], acc[i][5] + bias[5],
                            acc[i][6] + bias[6], acc[i][7] + bias[7]);
    *(float4*)dst = o0;
    *(float4*)(dst + 4) = o1;
  }
}

// ---------------------------------------------------------------------------
// persistent LSTM scan, tag-embedded h protocol, r2 geometry, ASM-resident W.
// 64 blocks/sequence (128 total); block b owns rows [b*16,b*16+16).
// Thread (g=tid>>5, u=tid&31): row j=b*16+g, k-slice [u*32,+32), 4 gates
// -> 128 weight floats/thread, loaded via inline-asm global_load_dwordx4.
// Inline asm CANNOT be rematerialized by LLVM, so (unlike rounds 1-5, where
// the compiler sank the invariant loads back into the t-loop and re-streamed
// 256KB/block/step from L2: VGPR_Count 56, ~1.7us/step on the path) the 32
// f32x4 values must stay live in VGPRs (budget 256 via launch_bounds(512,2)).
// Per step: lane0 rotate-prefetches gx[t+1]; each thread polls its 2 h-words
// (tag in same 64b atom); stages into stride-33 LDS parity buffer (0-conflict
// layout, measured r2); ONE barrier; 128 literal-index FMAs; 5-level 32-lane
// butterfly; lane 0 gates + publishes (tag t+1 | h) as one 64b atom.
// ---------------------------------------------------------------------------
__global__ __launch_bounds__(SCAN_T, 2) void lstm_scan_kernel(
    const float* __restrict__ W_hh,
    const float* __restrict__ gx1, const float* __restrict__ gx2,
    const float* __restrict__ c01, const float* __restrict__ c02,
    u64* __restrict__ hb1, u64* __restrict__ hb2) {
  const int blk = blockIdx.x;
  const int seq = (blk >= NBLK) ? 1 : 0;
  const int b = blk - seq * NBLK;
  const float* __restrict__ gx = seq ? gx2 : gx1;
  u64* hb = seq ? hb2 : hb1;
  const float* c0 = seq ? c02 : c01;

  const int tid = threadIdx.x;
  const int g = tid >> 5;       // 0..15 : row within block
  const int u = tid & 31;       // 0..31 : 32-wide k-slice
  const int j = b * 16 + g;     // owned output row

  // per-gate base pointers for this thread's 32-float slice
  const float* wp0 = W_hh + (((size_t)(0 * H_DIM + j)) << 10) + (u << 5);
  const float* wp1 = W_hh + (((size_t)(1 * H_DIM + j)) << 10) + (u << 5);
  const float* wp2 = W_hh + (((size_t)(2 * H_DIM + j)) << 10) + (u << 5);
  const float* wp3 = W_hh + (((size_t)(3 * H_DIM + j)) << 10) + (u << 5);

  // asm-forced weight residency: 32 x global_load_dwordx4 (non-remat-able)
  f32x4 W0[8], W1[8], W2[8], W3[8];
#define ALD(dst, base, OFF) \
  asm volatile("global_load_dwordx4 %0, %1, off offset:" OFF \
               : "=v"(dst) : "v"(base))
  ALD(W0[0], wp0, "0");  ALD(W0[1], wp0, "16"); ALD(W0[2], wp0, "32");
  ALD(W0[3], wp0, "48"); ALD(W0[4], wp0, "64"); ALD(W0[5], wp0, "80");
  ALD(W0[6], wp0, "96"); ALD(W0[7], wp0, "112");
  ALD(W1[0], wp1, "0");  ALD(W1[1], wp1, "16"); ALD(W1[2], wp1, "32");
  ALD(W1[3], wp1, "48"); ALD(W1[4], wp1, "64"); ALD(W1[5], wp1, "80");
  ALD(W1[6], wp1, "96"); ALD(W1[7], wp1, "112");
  ALD(W2[0], wp2, "0");  ALD(W2[1], wp2, "16"); ALD(W2[2], wp2, "32");
  ALD(W2[3], wp2, "48"); ALD(W2[4], wp2, "64"); ALD(W2[5], wp2, "80");
  ALD(W2[6], wp2, "96"); ALD(W2[7], wp2, "112");
  ALD(W3[0], wp3, "0");  ALD(W3[1], wp3, "16"); ALD(W3[2], wp3, "32");
  ALD(W3[3], wp3, "48"); ALD(W3[4], wp3, "64"); ALD(W3[5], wp3, "80");
  ALD(W3[6], wp3, "96"); ALD(W3[7], wp3, "112");
#undef ALD
  asm volatile("s_waitcnt vmcnt(0)" ::: "memory");
  __builtin_amdgcn_sched_barrier(0);  // rule #18: nothing moves above the wait

  float c = (u == 0) ? c0[j] : 0.0f;

  __shared__ float sh[2][32 * 33];  // parity dbuf; stride 33 = 0-conflict (r2)

  const int i0 = tid * 2;           // this thread's 2 h-word slots
  const int stg = (i0 >> 5) * 33 + (i0 & 31);   // staging offset (floats)

  // gx prefetch: current-step values in gxc*, next-step issued each iter
  float gxc0 = 0.f, gxc1 = 0.f, gxc2 = 0.f, gxc3 = 0.f;
  if (u == 0) {
    const float* gp = gx + j;
    gxc0 = gp[0];
    gxc1 = gp[H_DIM];
    gxc2 = gp[2 * H_DIM];
    gxc3 = gp[3 * H_DIM];
  }

  for (int t = 0; t < L_SEQ; ++t) {
    // issue next step's gx loads (hidden under this step's poll + compute)
    float gxn0 = 0.f, gxn1 = 0.f, gxn2 = 0.f, gxn3 = 0.f;
    if (u == 0) {
      const int tp = (t + 1 < L_SEQ) ? t + 1 : t;
      const float* gp = gx + (size_t)tp * (4 * H_DIM) + j;
      gxn0 = gp[0];
      gxn1 = gp[H_DIM];
      gxn2 = gp[2 * H_DIM];
      gxn3 = gp[3 * H_DIM];
    }
    // poll both h-words with overlapped loads (tag embedded in same atom)
    const u64* src = hb + ((t & 1) << 10) + i0;
    const unsigned tg = (unsigned)t;
    u64 w0, w1;
    for (;;) {
      w0 = __hip_atomic_load(src,     __ATOMIC_RELAXED, __HIP_MEMORY_SCOPE_AGENT);
      w1 = __hip_atomic_load(src + 1, __ATOMIC_RELAXED, __HIP_MEMORY_SCOPE_AGENT);
      if (((unsigned)(w0 >> 32) == tg) & ((unsigned)(w1 >> 32) == tg)) break;
    }
    float* sb = &sh[t & 1][0];
    sb[stg + 0] = __uint_as_float((unsigned)w0);
    sb[stg + 1] = __uint_as_float((unsigned)w1);
    __syncthreads();  // the only barrier per step (parity dbuf covers WAR)
    // 128 FMAs, all literal indices (f32x4 lanes + constant LDS offsets)
    const float* hs = sb + u * 33;
    float a0 = 0.f, a1 = 0.f, a2 = 0.f, a3 = 0.f;
#define FMA_GRP(i) do {                                                  \
    const float h0 = hs[4*(i)+0], h1 = hs[4*(i)+1];                      \
    const float h2 = hs[4*(i)+2], h3 = hs[4*(i)+3];                      \
    a0 = fmaf(W0[i][0], h0, a0); a0 = fmaf(W0[i][1], h1, a0);            \
    a0 = fmaf(W0[i][2], h2, a0); a0 = fmaf(W0[i][3], h3, a0);            \
    a1 = fmaf(W1[i][0], h0, a1); a1 = fmaf(W1[i][1], h1, a1);            \
    a1 = fmaf(W1[i][2], h2, a1); a1 = fmaf(W1[i][3], h3, a1);            \
    a2 = fmaf(W2[i][0], h0, a2); a2 = fmaf(W2[i][1], h1, a2);            \
    a2 = fmaf(W2[i][2], h2, a2); a2 = fmaf(W2[i][3], h3, a2);            \
    a3 = fmaf(W3[i][0], h0, a3); a3 = fmaf(W3[i][1], h1, a3);            \
    a3 = fmaf(W3[i][2], h2, a3); a3 = fmaf(W3[i][3], h3, a3); } while (0)
    FMA_GRP(0); FMA_GRP(1); FMA_GRP(2); FMA_GRP(3);
    FMA_GRP(4); FMA_GRP(5); FMA_GRP(6); FMA_GRP(7);
#undef FMA_GRP
    // 32-lane butterfly reduce (lanes u and u+32 hold identical values)
#pragma unroll
    for (int offx = 16; offx >= 1; offx >>= 1) {
      a0 += __shfl_xor(a0, offx, 32);
      a1 += __shfl_xor(a1, offx, 32);
      a2 += __shfl_xor(a2, offx, 32);
      a3 += __shfl_xor(a3, offx, 32);
    }
    if (u == 0) {
      const float gi = a0 + gxc0;
      const float gf = a1 + gxc1;
      const float gg = a2 + gxc2;
      const float go = a3 + gxc3;
      c = sigmoid_f(gf) * c + sigmoid_f(gi) * tanh_f(gg);
      const float hn = sigmoid_f(go) * tanh_f(c);
      const u64 pk = ((u64)(unsigned)(t + 1) << 32) | (u64)__float_as_uint(hn);
      __hip_atomic_store(hb + (((t + 1) & 1) << 10) + j, pk,
                         __ATOMIC_RELAXED, __HIP_MEMORY_SCOPE_AGENT);
      gxc0 = gxn0; gxc1 = gxn1; gxc2 = gxn2; gxc3 = gxn3;
    }
  }
}

// ---------------------------------------------------------------------------
// head: feat = [v1, v2, |v1-v2|, v1*v2]; out = fc2_w @ (fc1_w@feat + fc1_b) + fc2_b
// reads the packed final-h buffers (parity 0 holds tag-2048 values)
// ---------------------------------------------------------------------------
__global__ __launch_bounds__(512) void head_kernel(
    const u64* __restrict__ h1p, const u64* __restrict__ h2p,
    const float* __restrict__ fc1_w, const float* __restrict__ fc1_b,
    const float* __restrict__ fc2_w, const float* __restrict__ fc2_b,
    float* __restrict__ out) {
  __shared__ float feat[4 * H_DIM];
  __shared__ float yv[512];
  const int tid = threadIdx.x;
  for (int i = tid; i < H_DIM; i += 512) {
    const float a = __uint_as_float((unsigned)h1p[i]);
    const float bsv = __uint_as_float((unsigned)h2p[i]);
    feat[i] = a;
    feat[H_DIM + i] = bsv;
    feat[2 * H_DIM + i] = fabsf(a - bsv);
    feat[3 * H_DIM + i] = a * bsv;
  }
  __syncthreads();
  float s = fc1_b[tid];
  const float4* wr = (const float4*)(fc1_w + (size_t)tid * (4 * H_DIM));
#pragma unroll 4
  for (int k4 = 0; k4 < H_DIM; ++k4) {
    const float4 wv = wr[k4];
    const float4 fv = *(const float4*)&feat[k4 * 4];
    s = fmaf(wv.x, fv.x, s);
    s = fmaf(wv.y, fv.y, s);
    s = fmaf(wv.z, fv.z, s);
    s = fmaf(wv.w, fv.w, s);
  }
  yv[tid] = s;
  __syncthreads();
  if (tid < 64) {
    float s0 = 0.f, s1 = 0.f;
    for (int i = tid; i < 512; i += 64) {
      s0 = fmaf(fc2_w[i], yv[i], s0);
      s1 = fmaf(fc2_w[512 + i], yv[i], s1);
    }
#pragma unroll
    for (int off = 32; off >= 1; off >>= 1) {
      s0 += __shfl_down(s0, off);
      s1 += __shfl_down(s1, off);
    }
    if (tid == 0) {
      out[0] = s0 + fc2_b[0];
      out[1] = s1 + fc2_b[1];
    }
  }
}

// ---------------------------------------------------------------------------
extern "C" void kernel_launch(void* const* d_in, const int* in_sizes, int n_in,
                              void* d_out, int out_size, void* d_ws, size_t ws_size,
                              hipStream_t stream) {
  const int*   s1    = (const int*)  d_in[0];
  const int*   s2    = (const int*)  d_in[1];
  const float* emb   = (const float*)d_in[2];
  const float* W_ih  = (const float*)d_in[3];
  const float* W_hh  = (const float*)d_in[4];
  const float* b_ih  = (const float*)d_in[5];
  const float* b_hh  = (const float*)d_in[6];
  const float* h01   = (const float*)d_in[7];
  const float* c01   = (const float*)d_in[8];
  const float* h02   = (const float*)d_in[9];
  const float* c02   = (const float*)d_in[10];
  const float* fc1_w = (const float*)d_in[11];
  const float* fc1_b = (const float*)d_in[12];
  const float* fc2_w = (const float*)d_in[13];
  const float* fc2_b = (const float*)d_in[14];
  float* out = (float*)d_out;

  // workspace layout
  const size_t GX = (size_t)L_SEQ * 4 * H_DIM;  // 8M floats per sequence
  float* ws = (float*)d_ws;
  float* gx1 = ws;
  float* gx2 = ws + GX;
  u64* hb1 = (u64*)(ws + 2 * GX);      // [2][1024] packed (tag|h) double buffer
  u64* hb2 = hb1 + 2 * H_DIM;

  init_kernel<<<1, 256, 0, stream>>>(h01, h02, hb1, hb2);

  gemm_gx_kernel<<<dim3(32, 16, 2), 256, 0, stream>>>(
      s1, s2, emb, W_ih, b_ih, b_hh, gx1, gx2);

  void* args[] = { (void*)&W_hh, (void*)&gx1, (void*)&gx2, (void*)&c01,
                   (void*)&c02, (void*)&hb1, (void*)&hb2 };
  hipLaunchCooperativeKernel(reinterpret_cast<void*>(lstm_scan_kernel),
                             dim3(2 * NBLK), dim3(SCAN_T), args, 0, stream);

  head_kernel<<<1, 512, 0, stream>>>(hb1, hb2, fc1_w, fc1_b, fc2_w, fc2_b, out);
}

// Round 7
// 4398.856 us; speedup vs baseline: 2.0600x; 1.5755x over previous
//
#include <hip/hip_runtime.h>
#include <cstdint>
#include <cstddef>

#define L_SEQ 2048
#define H_DIM 1024
#define NBLK  64      // scan blocks per sequence (16 rows each)
#define SCAN_T 512    // threads per block (scan and worker roles)
#define NWORK 128     // gemm worker blocks (idle CUs)
#define TTILE 128     // tokens per gx tile
#define NTILE (L_SEQ / TTILE)   // 16 tiles per sequence
#define AGENT __HIP_MEMORY_SCOPE_AGENT

typedef unsigned long long u64;
typedef __attribute__((ext_vector_type(4))) float f32x4;
typedef __attribute__((ext_vector_type(4))) unsigned int u32x4;

__device__ __forceinline__ float sigmoid_f(float x) {
  return 1.0f / (1.0f + __expf(-x));
}
__device__ __forceinline__ float tanh_f(float x) {
  return 1.0f - 2.0f / (__expf(2.0f * x) + 1.0f);
}

// ---------------------------------------------------------------------------
// init: pack h0 with tag 0 into parity-buffer 0; sentinels into buffer 1;
// zero the gx tile-ready counters.
// ---------------------------------------------------------------------------
__global__ void init_kernel(const float* __restrict__ h01, const float* __restrict__ h02,
                            u64* __restrict__ hb1, u64* __restrict__ hb2,
                            int* __restrict__ done) {
  const int tid = threadIdx.x;  // 256 threads
  if (tid < 2 * NTILE) done[tid] = 0;
  for (int i = tid; i < H_DIM; i += 256) {
    hb1[i] = (u64)__float_as_uint(h01[i]);          // tag 0 | h0 bits
    hb2[i] = (u64)__float_as_uint(h02[i]);
    hb1[H_DIM + i] = 0x7FFFFFFFull << 32;           // sentinel tag
    hb2[H_DIM + i] = 0x7FFFFFFFull << 32;
  }
}

// ---------------------------------------------------------------------------
// fused cooperative kernel: blocks [0,128) = LSTM scan (r6 core, 3.07us/step),
// blocks [128,256) = gx GEMM workers on the otherwise-idle CUs.
//
// Workers: gx = emb[tok] @ W_ih^T + (b_ih+b_hh), computed as 128x128 tiles in
// t-major order (global tile idx g: tau=g>>6, s=(g>>5)&1, n=g&31). Epilogue
// stores are agent-scope (write-through to LLC: no kernel-boundary flush
// exists mid-kernel), then one RELEASE fetch_add on done[s*16+tau]; a tile is
// consumable when its counter reaches 32.
//
// Scan: identical to r6 (asm-resident weights, tag-embedded u64 h protocol,
// stride-33 LDS parity buffer, one barrier/step) except (a) gx loads are
// agent-scope (prefetched a full ~3us step ahead, latency hidden), (b) a
// tile gate once per 128 steps (ACQUIRE poll by tid0 + barrier), (c) the
// two-word poll is a single global_load_dwordx4 sc0 sc1 — per-8B tags make
// any 16B tearing harmless; halves poll issue + TCC requests.
// ---------------------------------------------------------------------------
__global__ __launch_bounds__(SCAN_T, 2) void fused_kernel(
    const float* __restrict__ W_hh,
    const int* __restrict__ s1, const int* __restrict__ s2,
    const float* __restrict__ emb, const float* __restrict__ W_ih,
    const float* __restrict__ b_ih, const float* __restrict__ b_hh,
    float* __restrict__ gx1, float* __restrict__ gx2,
    const float* __restrict__ c01, const float* __restrict__ c02,
    u64* __restrict__ hb1, u64* __restrict__ hb2,
    int* __restrict__ done) {
  __shared__ float smem[4096];  // 16KB: worker A/B tiles, scan parity buffers
  const int blk = blockIdx.x;
  const int tid = threadIdx.x;

  if (blk >= 2 * NBLK) {
    // ------------------------------ worker path ---------------------------
    const int wid = blk - 2 * NBLK;
    float (*As)[128] = (float(*)[128])smem;          // [16][128]
    float (*Bs)[128] = (float(*)[128])(smem + 2048); // [16][128]
    const int ti = tid >> 5;   // 0..15 : 8 output rows each
    const int tj = tid & 31;   // 0..31 : 4 output cols each
    const int lr = tid >> 2;   // 0..127: tile row this thread stages
    const int k4 = (tid & 3) * 4;

    for (int g = wid; g < 2 * NTILE * 32; g += NWORK) {
      const int tau = g >> 6;
      const int s   = (g >> 5) & 1;
      const int n   = g & 31;
      const int m0  = tau * TTILE;
      const int n0  = n * 128;
      const int* __restrict__ tok = s ? s2 : s1;
      float* __restrict__ gxp = s ? gx2 : gx1;

      const int arow = tok[m0 + lr];
      const float* aptr = emb + (size_t)arow * H_DIM + k4;
      const float* bptr = W_ih + (size_t)(n0 + lr) * H_DIM + k4;

      float acc[8][4];
#pragma unroll
      for (int i = 0; i < 8; ++i)
#pragma unroll
        for (int jj = 0; jj < 4; ++jj) acc[i][jj] = 0.f;

      for (int k0 = 0; k0 < H_DIM; k0 += 16) {
        const float4 av = *(const float4*)(aptr + k0);
        const float4 bv = *(const float4*)(bptr + k0);
        __syncthreads();  // protect previous iteration's LDS reads
        As[k4 + 0][lr] = av.x; As[k4 + 1][lr] = av.y;
        As[k4 + 2][lr] = av.z; As[k4 + 3][lr] = av.w;
        Bs[k4 + 0][lr] = bv.x; Bs[k4 + 1][lr] = bv.y;
        Bs[k4 + 2][lr] = bv.z; Bs[k4 + 3][lr] = bv.w;
        __syncthreads();
#pragma unroll
        for (int k = 0; k < 16; ++k) {
          float a[8], bb[4];
          *(float4*)&a[0] = *(const float4*)&As[k][ti * 8];
          *(float4*)&a[4] = *(const float4*)&As[k][ti * 8 + 4];
          *(float4*)&bb[0] = *(const float4*)&Bs[k][tj * 4];
#pragma unroll
          for (int i = 0; i < 8; ++i)
#pragma unroll
            for (int jj = 0; jj < 4; ++jj)
              acc[i][jj] = fmaf(a[i], bb[jj], acc[i][jj]);
        }
      }

      float bias[4];
#pragma unroll
      for (int jj = 0; jj < 4; ++jj) {
        const int nn = n0 + tj * 4 + jj;
        bias[jj] = b_ih[nn] + b_hh[nn];
      }
#pragma unroll
      for (int i = 0; i < 8; ++i) {
        const int m = m0 + ti * 8 + i;
        unsigned* dst = (unsigned*)(gxp + (size_t)m * (4 * H_DIM) + n0 + tj * 4);
#pragma unroll
        for (int jj = 0; jj < 4; ++jj)
          __hip_atomic_store(dst + jj, __float_as_uint(acc[i][jj] + bias[jj]),
                             __ATOMIC_RELAXED, AGENT);
      }
      __syncthreads();  // drains all threads' stores (vmcnt 0 before barrier)
      if (tid == 0)
        __hip_atomic_fetch_add(&done[s * NTILE + tau], 1, __ATOMIC_RELEASE, AGENT);
    }
    return;
  }

  // -------------------------------- scan path -----------------------------
  const int seq = (blk >= NBLK) ? 1 : 0;
  const int b = blk - seq * NBLK;
  const float* __restrict__ gx = seq ? gx2 : gx1;
  u64* hb = seq ? hb2 : hb1;
  const float* c0 = seq ? c02 : c01;
  int* dct = done + seq * NTILE;

  const int g = tid >> 5;       // 0..15 : row within block
  const int u = tid & 31;       // 0..31 : 32-wide k-slice
  const int j = b * 16 + g;     // owned output row

  // per-gate base pointers for this thread's 32-float slice
  const float* wp0 = W_hh + (((size_t)(0 * H_DIM + j)) << 10) + (u << 5);
  const float* wp1 = W_hh + (((size_t)(1 * H_DIM + j)) << 10) + (u << 5);
  const float* wp2 = W_hh + (((size_t)(2 * H_DIM + j)) << 10) + (u << 5);
  const float* wp3 = W_hh + (((size_t)(3 * H_DIM + j)) << 10) + (u << 5);

  // asm-forced weight residency (non-remat-able; allocator keeps in VGPR/AGPR)
  f32x4 W0[8], W1[8], W2[8], W3[8];
#define ALD(dst, base, OFF) \
  asm volatile("global_load_dwordx4 %0, %1, off offset:" OFF \
               : "=v"(dst) : "v"(base))
  ALD(W0[0], wp0, "0");  ALD(W0[1], wp0, "16"); ALD(W0[2], wp0, "32");
  ALD(W0[3], wp0, "48"); ALD(W0[4], wp0, "64"); ALD(W0[5], wp0, "80");
  ALD(W0[6], wp0, "96"); ALD(W0[7], wp0, "112");
  ALD(W1[0], wp1, "0");  ALD(W1[1], wp1, "16"); ALD(W1[2], wp1, "32");
  ALD(W1[3], wp1, "48"); ALD(W1[4], wp1, "64"); ALD(W1[5], wp1, "80");
  ALD(W1[6], wp1, "96"); ALD(W1[7], wp1, "112");
  ALD(W2[0], wp2, "0");  ALD(W2[1], wp2, "16"); ALD(W2[2], wp2, "32");
  ALD(W2[3], wp2, "48"); ALD(W2[4], wp2, "64"); ALD(W2[5], wp2, "80");
  ALD(W2[6], wp2, "96"); ALD(W2[7], wp2, "112");
  ALD(W3[0], wp3, "0");  ALD(W3[1], wp3, "16"); ALD(W3[2], wp3, "32");
  ALD(W3[3], wp3, "48"); ALD(W3[4], wp3, "64"); ALD(W3[5], wp3, "80");
  ALD(W3[6], wp3, "96"); ALD(W3[7], wp3, "112");
#undef ALD
  asm volatile("s_waitcnt vmcnt(0)" ::: "memory");
  __builtin_amdgcn_sched_barrier(0);

  float c = (u == 0) ? c0[j] : 0.0f;

  const int i0 = tid * 2;                        // this thread's 2 h-words
  const int stg = (i0 >> 5) * 33 + (i0 & 31);    // staging offset (floats)

  // gate for tile 0, then prefetch gx[0]
  if (tid == 0) {
    while (__hip_atomic_load(&dct[0], __ATOMIC_ACQUIRE, AGENT) < 32) { }
  }
  __syncthreads();

  float gxc0 = 0.f, gxc1 = 0.f, gxc2 = 0.f, gxc3 = 0.f;
  if (u == 0) {
    const unsigned* gp = (const unsigned*)(gx + j);
    gxc0 = __uint_as_float(__hip_atomic_load(gp,            __ATOMIC_RELAXED, AGENT));
    gxc1 = __uint_as_float(__hip_atomic_load(gp + H_DIM,     __ATOMIC_RELAXED, AGENT));
    gxc2 = __uint_as_float(__hip_atomic_load(gp + 2 * H_DIM, __ATOMIC_RELAXED, AGENT));
    gxc3 = __uint_as_float(__hip_atomic_load(gp + 3 * H_DIM, __ATOMIC_RELAXED, AGENT));
  }

  for (int t = 0; t < L_SEQ; ++t) {
    const int tp = (t + 1 < L_SEQ) ? t + 1 : t;
    // gate the tile containing step tp (workers run far ahead; ~never spins
    // after the first tile)
    if (tp != t && (tp & (TTILE - 1)) == 0) {
      if (tid == 0) {
        while (__hip_atomic_load(&dct[tp >> 7], __ATOMIC_ACQUIRE, AGENT) < 32) { }
      }
      __syncthreads();
    }
    // issue next step's gx loads (hidden under this step's poll + compute)
    float gxn0 = 0.f, gxn1 = 0.f, gxn2 = 0.f, gxn3 = 0.f;
    if (u == 0) {
      const unsigned* gp = (const unsigned*)(gx + (size_t)tp * (4 * H_DIM) + j);
      gxn0 = __uint_as_float(__hip_atomic_load(gp,            __ATOMIC_RELAXED, AGENT));
      gxn1 = __uint_as_float(__hip_atomic_load(gp + H_DIM,     __ATOMIC_RELAXED, AGENT));
      gxn2 = __uint_as_float(__hip_atomic_load(gp + 2 * H_DIM, __ATOMIC_RELAXED, AGENT));
      gxn3 = __uint_as_float(__hip_atomic_load(gp + 3 * H_DIM, __ATOMIC_RELAXED, AGENT));
    }
    // poll both h-words with ONE dwordx4 (sc0 sc1 = LLC-coherent); each 8B
    // half carries its own tag, so 16B tearing is harmless
    const u64* src = hb + ((t & 1) << 10) + i0;
    const unsigned tg = (unsigned)t;
    u32x4 pw;
    for (;;) {
      asm volatile("global_load_dwordx4 %0, %1, off sc0 sc1\n\t"
                   "s_waitcnt vmcnt(0)"
                   : "=v"(pw) : "v"(src) : "memory");
      if ((pw[1] == tg) & (pw[3] == tg)) break;
    }
    float* sb = smem + (t & 1) * 1056;
    sb[stg + 0] = __uint_as_float(pw[0]);
    sb[stg + 1] = __uint_as_float(pw[2]);
    __syncthreads();  // the only per-step barrier (parity dbuf covers WAR)
    // 128 FMAs, all literal indices
    const float* hs = sb + u * 33;
    float a0 = 0.f, a1 = 0.f, a2 = 0.f, a3 = 0.f;
#define FMA_GRP(i) do {                                                  \
    const float h0 = hs[4*(i)+0], h1 = hs[4*(i)+1];                      \
    const float h2 = hs[4*(i)+2], h3 = hs[4*(i)+3];                      \
    a0 = fmaf(W0[i][0], h0, a0); a0 = fmaf(W0[i][1], h1, a0);            \
    a0 = fmaf(W0[i][2], h2, a0); a0 = fmaf(W0[i][3], h3, a0);            \
    a1 = fmaf(W1[i][0], h0, a1); a1 = fmaf(W1[i][1], h1, a1);            \
    a1 = fmaf(W1[i][2], h2, a1); a1 = fmaf(W1[i][3], h3, a1);            \
    a2 = fmaf(W2[i][0], h0, a2); a2 = fmaf(W2[i][1], h1, a2);            \
    a2 = fmaf(W2[i][2], h2, a2); a2 = fmaf(W2[i][3], h3, a2);            \
    a3 = fmaf(W3[i][0], h0, a3); a3 = fmaf(W3[i][1], h1, a3);            \
    a3 = fmaf(W3[i][2], h2, a3); a3 = fmaf(W3[i][3], h3, a3); } while (0)
    FMA_GRP(0); FMA_GRP(1); FMA_GRP(2); FMA_GRP(3);
    FMA_GRP(4); FMA_GRP(5); FMA_GRP(6); FMA_GRP(7);
#undef FMA_GRP
    // 32-lane butterfly reduce (lanes u and u+32 hold identical values)
#pragma unroll
    for (int offx = 16; offx >= 1; offx >>= 1) {
      a0 += __shfl_xor(a0, offx, 32);
      a1 += __shfl_xor(a1, offx, 32);
      a2 += __shfl_xor(a2, offx, 32);
      a3 += __shfl_xor(a3, offx, 32);
    }
    if (u == 0) {
      const float gi = a0 + gxc0;
      const float gf = a1 + gxc1;
      const float gg = a2 + gxc2;
      const float go = a3 + gxc3;
      c = sigmoid_f(gf) * c + sigmoid_f(gi) * tanh_f(gg);
      const float hn = sigmoid_f(go) * tanh_f(c);
      const u64 pk = ((u64)(unsigned)(t + 1) << 32) | (u64)__float_as_uint(hn);
      __hip_atomic_store(hb + (((t + 1) & 1) << 10) + j, pk,
                         __ATOMIC_RELAXED, AGENT);
      gxc0 = gxn0; gxc1 = gxn1; gxc2 = gxn2; gxc3 = gxn3;
    }
  }
}

// ---------------------------------------------------------------------------
// head: feat = [v1, v2, |v1-v2|, v1*v2]; out = fc2_w @ (fc1_w@feat + fc1_b) + fc2_b
// ---------------------------------------------------------------------------
__global__ __launch_bounds__(512) void head_kernel(
    const u64* __restrict__ h1p, const u64* __restrict__ h2p,
    const float* __restrict__ fc1_w, const float* __restrict__ fc1_b,
    const float* __restrict__ fc2_w, const float* __restrict__ fc2_b,
    float* __restrict__ out) {
  __shared__ float feat[4 * H_DIM];
  __shared__ float yv[512];
  const int tid = threadIdx.x;
  for (int i = tid; i < H_DIM; i += 512) {
    const float a = __uint_as_float((unsigned)h1p[i]);
    const float bsv = __uint_as_float((unsigned)h2p[i]);
    feat[i] = a;
    feat[H_DIM + i] = bsv;
    feat[2 * H_DIM + i] = fabsf(a - bsv);
    feat[3 * H_DIM + i] = a * bsv;
  }
  __syncthreads();
  float s = fc1_b[tid];
  const float4* wr = (const float4*)(fc1_w + (size_t)tid * (4 * H_DIM));
#pragma unroll 4
  for (int k4 = 0; k4 < H_DIM; ++k4) {
    const float4 wv = wr[k4];
    const float4 fv = *(const float4*)&feat[k4 * 4];
    s = fmaf(wv.x, fv.x, s);
    s = fmaf(wv.y, fv.y, s);
    s = fmaf(wv.z, fv.z, s);
    s = fmaf(wv.w, fv.w, s);
  }
  yv[tid] = s;
  __syncthreads();
  if (tid < 64) {
    float s0 = 0.f, s1 = 0.f;
    for (int i = tid; i < 512; i += 64) {
      s0 = fmaf(fc2_w[i], yv[i], s0);
      s1 = fmaf(fc2_w[512 + i], yv[i], s1);
    }
#pragma unroll
    for (int off = 32; off >= 1; off >>= 1) {
      s0 += __shfl_down(s0, off);
      s1 += __shfl_down(s1, off);
    }
    if (tid == 0) {
      out[0] = s0 + fc2_b[0];
      out[1] = s1 + fc2_b[1];
    }
  }
}

// ---------------------------------------------------------------------------
extern "C" void kernel_launch(void* const* d_in, const int* in_sizes, int n_in,
                              void* d_out, int out_size, void* d_ws, size_t ws_size,
                              hipStream_t stream) {
  const int*   s1    = (const int*)  d_in[0];
  const int*   s2    = (const int*)  d_in[1];
  const float* emb   = (const float*)d_in[2];
  const float* W_ih  = (const float*)d_in[3];
  const float* W_hh  = (const float*)d_in[4];
  const float* b_ih  = (const float*)d_in[5];
  const float* b_hh  = (const float*)d_in[6];
  const float* h01   = (const float*)d_in[7];
  const float* c01   = (const float*)d_in[8];
  const float* h02   = (const float*)d_in[9];
  const float* c02   = (const float*)d_in[10];
  const float* fc1_w = (const float*)d_in[11];
  const float* fc1_b = (const float*)d_in[12];
  const float* fc2_w = (const float*)d_in[13];
  const float* fc2_b = (const float*)d_in[14];
  float* out = (float*)d_out;

  // workspace layout
  const size_t GX = (size_t)L_SEQ * 4 * H_DIM;  // 8M floats per sequence
  float* ws = (float*)d_ws;
  float* gx1 = ws;
  float* gx2 = ws + GX;
  u64* hb1 = (u64*)(ws + 2 * GX);      // [2][1024] packed (tag|h) double buffer
  u64* hb2 = hb1 + 2 * H_DIM;
  int* done = (int*)(hb2 + 2 * H_DIM); // 32 tile-ready counters

  init_kernel<<<1, 256, 0, stream>>>(h01, h02, hb1, hb2, done);

  void* args[] = { (void*)&W_hh, (void*)&s1, (void*)&s2, (void*)&emb,
                   (void*)&W_ih, (void*)&b_ih, (void*)&b_hh,
                   (void*)&gx1, (void*)&gx2, (void*)&c01, (void*)&c02,
                   (void*)&hb1, (void*)&hb2, (void*)&done };
  hipLaunchCooperativeKernel(reinterpret_cast<void*>(fused_kernel),
                             dim3(2 * NBLK + NWORK), dim3(SCAN_T), args, 0, stream);

  head_kernel<<<1, 512, 0, stream>>>(hb1, hb2, fc1_w, fc1_b, fc2_w, fc2_b, out);
}